// Round 15
// baseline (1575.632 us; speedup 1.0000x reference)
//
#include <hip/hip_runtime.h>
#include <math.h>
#include <stdint.h>

#define N_CTX 4096
#define DIM 512
#define NPERS 16
#define KTOT (NPERS * DIM)   // 8192
#define EPS_NN 0.1f
#define TOPK_K 30

#define DELTA 3e-4f          // ambiguity margin (>= 12x the 2*eps ~ 2.4e-5 bound)
#define CAP 64               // max candidates per row

#define BM 128               // MFMA output tile
#define BK 64                // K-step (bf16 elems)
#define NKSTEP (KTOT / BK)   // 128
#define CHUNK 16384          // bytes per (panel, k-step) LDS image

typedef __attribute__((ext_vector_type(8))) short bfrag;   // 8 bf16 = 4 VGPR
typedef __attribute__((ext_vector_type(4))) float f32x4;

// round-to-nearest-even float -> bf16 bits
__device__ __forceinline__ unsigned short f2bf(float f) {
  unsigned u = __float_as_uint(f);
  unsigned r = u + 0x7FFFu + ((u >> 16) & 1u);
  return (unsigned short)(r >> 16);
}

#define SWZ(r, b) ((b) ^ (((r) & 7) << 4))

// stage 1 KB: 64 lanes x 16 B. ldst = wave-uniform LDS base; HW adds lane*16.
__device__ __forceinline__ void stage1k(const char* gsrc, char* ldst, int lane) {
#if __has_builtin(__builtin_amdgcn_global_load_lds)
  __builtin_amdgcn_global_load_lds(
      (const __attribute__((address_space(1))) unsigned int*)(uintptr_t)(gsrc + lane * 16),
      (__attribute__((address_space(3))) unsigned int*)(uintptr_t)ldst, 16, 0, 0);
#else
  *reinterpret_cast<uint4*>(ldst + lane * 16) =
      *reinterpret_cast<const uint4*>(gsrc + lane * 16);
#endif
}

// ---------------------------------------------------------------------------
// Kernel 1 (fallback only): invr[p][n] = 0.25 / max(||c_n * w_p||, 1e-12)
// ---------------------------------------------------------------------------
__global__ __launch_bounds__(256) void norms_kernel(
    const float* __restrict__ ctx, const float* __restrict__ w,
    float* __restrict__ invr, int* __restrict__ gcount) {
  int wid = threadIdx.x >> 6;
  int lane = threadIdx.x & 63;
  int gid = blockIdx.x * 4 + wid;          // 0 .. 65535
  if (blockIdx.x == 0 && threadIdx.x == 0) gcount[0] = 0;
  int p = gid >> 12;
  int n = gid & (N_CTX - 1);
  const float4* c4 = reinterpret_cast<const float4*>(ctx + (size_t)n * DIM + lane * 8);
  const float4* w4 = reinterpret_cast<const float4*>(w + (size_t)p * DIM + lane * 8);
  float4 c0 = c4[0], c1 = c4[1];
  float4 w0 = w4[0], w1 = w4[1];
  float s = 0.f, v;
  v = c0.x * w0.x; s = fmaf(v, v, s);
  v = c0.y * w0.y; s = fmaf(v, v, s);
  v = c0.z * w0.z; s = fmaf(v, v, s);
  v = c0.w * w0.w; s = fmaf(v, v, s);
  v = c1.x * w1.x; s = fmaf(v, v, s);
  v = c1.y * w1.y; s = fmaf(v, v, s);
  v = c1.z * w1.z; s = fmaf(v, v, s);
  v = c1.w * w1.w; s = fmaf(v, v, s);
#pragma unroll
  for (int off = 32; off; off >>= 1) s += __shfl_down(s, off, 64);
  if (lane == 0) invr[(size_t)p * N_CTX + n] = 0.25f / fmaxf(sqrtf(s), 1e-12f);
}

// ---------------------------------------------------------------------------
// Kernel 1+1b FUSED (unchanged from R14, + gcount zeroing by thread 0).
// ---------------------------------------------------------------------------
__global__ __launch_bounds__(256) void split_norms_kernel(
    const float* __restrict__ ctx, const float* __restrict__ w,
    float* __restrict__ invr, unsigned short* __restrict__ Fhi,
    unsigned short* __restrict__ Flo, int* __restrict__ gcount) {
  const int tid = blockIdx.x * 256 + threadIdx.x;   // 0 .. 4096*64-1
  if (tid == 0) gcount[0] = 0;
  const int n = tid >> 6;                 // wave-uniform (wave = 64 aligned)
  const int db = tid & 63;                // lane = 8-col block within 512-dim
  const int d0 = db * 8;
  const int P = n >> 7;                   // panel
  const int r = n & 127;                  // row within panel
  const int sl = db & 7;                  // 16B slot within k-step chunk
  const int swzoff = r * 128 + ((sl * 16) ^ ((r & 7) << 4));

  const float4 c0 = *reinterpret_cast<const float4*>(ctx + (size_t)n * DIM + d0);
  const float4 c1 = *reinterpret_cast<const float4*>(ctx + (size_t)n * DIM + d0 + 4);

#pragma unroll
  for (int p = 0; p < NPERS; ++p) {
    const float4 w0 = *reinterpret_cast<const float4*>(w + (size_t)p * DIM + d0);
    const float4 w1 = *reinterpret_cast<const float4*>(w + (size_t)p * DIM + d0 + 4);

    float pr[8] = {c0.x * w0.x, c0.y * w0.y, c0.z * w0.z, c0.w * w0.w,
                   c1.x * w1.x, c1.y * w1.y, c1.z * w1.z, c1.w * w1.w};

    // norm: identical fmaf order + identical reduce tree as norms_kernel
    float s = 0.f;
#pragma unroll
    for (int j = 0; j < 8; ++j) s = fmaf(pr[j], pr[j], s);
#pragma unroll
    for (int off = 32; off; off >>= 1) s += __shfl_down(s, off, 64);
    const float stot = __shfl(s, 0, 64);
    const float sc = 0.25f / fmaxf(sqrtf(stot), 1e-12f);
    if (db == 0) invr[(size_t)p * N_CTX + n] = sc;

    unsigned hb[8], lb[8];
#pragma unroll
    for (int j = 0; j < 8; ++j) {
      const float f = pr[j] * sc;                  // == (c*w)*sc, as before
      hb[j] = f2bf(f);
      float hf = __uint_as_float(hb[j] << 16);
      lb[j] = f2bf(f - hf);
    }
    uint4 hv = make_uint4(hb[0] | (hb[1] << 16), hb[2] | (hb[3] << 16),
                          hb[4] | (hb[5] << 16), hb[6] | (hb[7] << 16));
    uint4 lv = make_uint4(lb[0] | (lb[1] << 16), lb[2] | (lb[3] << 16),
                          lb[4] | (lb[5] << 16), lb[6] | (lb[7] << 16));
    const int kstep = p * 8 + (db >> 3);           // k-step index
    const size_t base = (size_t)(P * 128 + kstep) * CHUNK + swzoff;
    *reinterpret_cast<uint4*>((char*)Fhi + base) = hv;
    *reinterpret_cast<uint4*>((char*)Flo + base) = lv;
  }
}

// ---------------------------------------------------------------------------
// Kernel 2 (fast): att = F F^T via bf16 MFMA, 3 products. UNCHANGED from R14
// (XCD-swizzled triangular grid; 493 us validated, values bit-identical).
// ---------------------------------------------------------------------------
__global__ __launch_bounds__(256, 2) void att_gemm_fast(
    const unsigned short* __restrict__ Fhi, const unsigned short* __restrict__ Flo,
    float* __restrict__ out) {
  const int bid0 = blockIdx.x;
  int bid = (bid0 & 7) * 66 + (bid0 >> 3);   // XCD-contiguous tile runs
  int by = 0;
  while (bid >= (by + 1) * 32 - ((by + 1) * by) / 2) ++by;
  const int bx = by + (bid - (by * 32 - (by * (by - 1)) / 2));

  __shared__ __align__(16) char Ahi[CHUNK];
  __shared__ __align__(16) char Alo[CHUNK];
  __shared__ __align__(16) char Bhi[CHUNK];
  __shared__ __align__(16) char Blo[CHUNK];

  const int t = threadIdx.x;
  const int lane = t & 63, wid = t >> 6;
  const int wr = wid >> 1, wc = wid & 1;
  const int woff = __builtin_amdgcn_readfirstlane(wid * 4096);

  const char* gAh = (const char*)Fhi + (size_t)by * NKSTEP * CHUNK + woff;
  const char* gAl = (const char*)Flo + (size_t)by * NKSTEP * CHUNK + woff;
  const char* gBh = (const char*)Fhi + (size_t)bx * NKSTEP * CHUNK + woff;
  const char* gBl = (const char*)Flo + (size_t)bx * NKSTEP * CHUNK + woff;

  f32x4 acc[4][4] = {};

  for (int s = 0; s < NKSTEP; ++s) {
    const size_t so = (size_t)s * CHUNK;
#pragma unroll
    for (int i = 0; i < 4; ++i) {
      stage1k(gAh + so + i * 1024, Ahi + woff + i * 1024, lane);
      stage1k(gAl + so + i * 1024, Alo + woff + i * 1024, lane);
      stage1k(gBh + so + i * 1024, Bhi + woff + i * 1024, lane);
      stage1k(gBl + so + i * 1024, Blo + woff + i * 1024, lane);
    }
    __syncthreads();

#pragma unroll
    for (int ks = 0; ks < 2; ++ks) {
      const int kb = ks * 64 + (lane >> 4) * 16;
      bfrag ah[4], al[4], bh[4], bl[4];
#pragma unroll
      for (int m = 0; m < 4; ++m) {
        const int r = wr * 64 + m * 16 + (lane & 15);
        const int off = r * 128 + SWZ(r, kb);
        ah[m] = *reinterpret_cast<const bfrag*>(Ahi + off);
        al[m] = *reinterpret_cast<const bfrag*>(Alo + off);
      }
#pragma unroll
      for (int n2 = 0; n2 < 4; ++n2) {
        const int r = wc * 64 + n2 * 16 + (lane & 15);
        const int off = r * 128 + SWZ(r, kb);
        bh[n2] = *reinterpret_cast<const bfrag*>(Bhi + off);
        bl[n2] = *reinterpret_cast<const bfrag*>(Blo + off);
      }
#pragma unroll
      for (int m = 0; m < 4; ++m)
#pragma unroll
        for (int n2 = 0; n2 < 4; ++n2) {
          acc[m][n2] = __builtin_amdgcn_mfma_f32_16x16x32_bf16(ah[m], bh[n2], acc[m][n2], 0, 0, 0);
          acc[m][n2] = __builtin_amdgcn_mfma_f32_16x16x32_bf16(ah[m], bl[n2], acc[m][n2], 0, 0, 0);
          acc[m][n2] = __builtin_amdgcn_mfma_f32_16x16x32_bf16(al[m], bh[n2], acc[m][n2], 0, 0, 0);
        }
    }
    __syncthreads();
  }

  const int Ro = by * BM, Co = bx * BM;
  const int col = lane & 15, rq = (lane >> 4) * 4;
#pragma unroll
  for (int m = 0; m < 4; ++m)
#pragma unroll
    for (int n2 = 0; n2 < 4; ++n2) {
      const int gr = Ro + wr * 64 + m * 16 + rq;
      const int gc = Co + wc * 64 + n2 * 16 + col;
#pragma unroll
      for (int j = 0; j < 4; ++j)
        out[(size_t)(gr + j) * N_CTX + gc] = acc[m][n2][j];
      if (bx != by) {
        *reinterpret_cast<float4*>(out + (size_t)gc * N_CTX + gr) =
            make_float4(acc[m][n2][0], acc[m][n2][1], acc[m][n2][2], acc[m][n2][3]);
      }
    }
}

// ---------------------------------------------------------------------------
// Kernel 2 (fallback): on-the-fly split + MFMA (used only if ws too small).
// ---------------------------------------------------------------------------
__device__ __forceinline__ void stage_half(char* __restrict__ hi_base,
                                           char* __restrict__ lo_base,
                                           const float4* cv, const float4* wv,
                                           float s, int r, int h) {
  unsigned hu[16], lu[16];
#pragma unroll
  for (int i = 0; i < 8; ++i) {
    float f[4] = {cv[i].x * wv[i].x * s, cv[i].y * wv[i].y * s,
                  cv[i].z * wv[i].z * s, cv[i].w * wv[i].w * s};
    unsigned hb[4], lb[4];
#pragma unroll
    for (int j = 0; j < 4; ++j) {
      hb[j] = f2bf(f[j]);
      float hf = __uint_as_float(hb[j] << 16);
      lb[j] = f2bf(f[j] - hf);
    }
    hu[2 * i] = hb[0] | (hb[1] << 16);
    hu[2 * i + 1] = hb[2] | (hb[3] << 16);
    lu[2 * i] = lb[0] | (lb[1] << 16);
    lu[2 * i + 1] = lb[2] | (lb[3] << 16);
  }
#pragma unroll
  for (int c = 0; c < 4; ++c) {
    int boff = r * 128 + SWZ(r, h * 64 + c * 16);
    *reinterpret_cast<uint4*>(hi_base + boff) =
        make_uint4(hu[4 * c], hu[4 * c + 1], hu[4 * c + 2], hu[4 * c + 3]);
    *reinterpret_cast<uint4*>(lo_base + boff) =
        make_uint4(lu[4 * c], lu[4 * c + 1], lu[4 * c + 2], lu[4 * c + 3]);
  }
}

__global__ __launch_bounds__(256, 2) void att_gemm(
    const float* __restrict__ ctx, const float* __restrict__ w,
    const float* __restrict__ invr, float* __restrict__ out) {
  const int bx = blockIdx.x, by = blockIdx.y;
  if (by > bx) return;

  __shared__ __align__(16) char Ahi[BM * 128];
  __shared__ __align__(16) char Alo[BM * 128];
  __shared__ __align__(16) char Bhi[BM * 128];
  __shared__ __align__(16) char Blo[BM * 128];

  const int t = threadIdx.x;
  const int lane = t & 63, wid = t >> 6;
  const int wr = wid >> 1, wc = wid & 1;
  const int Ro = by * BM, Co = bx * BM;
  const int srow = t >> 1;
  const int sh = t & 1;

  f32x4 acc[4][4] = {};

  for (int k0 = 0; k0 < KTOT; k0 += BK) {
    const int p = k0 >> 9;
    const int d0 = (k0 & (DIM - 1)) + sh * 32;

    float4 cva[8], cvb[8], wv[8];
    const float* wrow = w + (size_t)p * DIM + d0;
    const float* arow = ctx + (size_t)(Ro + srow) * DIM + d0;
    const float* brow = ctx + (size_t)(Co + srow) * DIM + d0;
#pragma unroll
    for (int i = 0; i < 8; ++i) {
      wv[i] = *reinterpret_cast<const float4*>(wrow + 4 * i);
      cva[i] = *reinterpret_cast<const float4*>(arow + 4 * i);
      cvb[i] = *reinterpret_cast<const float4*>(brow + 4 * i);
    }
    const float sA = invr[(size_t)p * N_CTX + Ro + srow];
    const float sB = invr[(size_t)p * N_CTX + Co + srow];

    __syncthreads();
    stage_half(Ahi, Alo, cva, wv, sA, srow, sh);
    stage_half(Bhi, Blo, cvb, wv, sB, srow, sh);
    __syncthreads();

#pragma unroll
    for (int ks = 0; ks < 2; ++ks) {
      const int kb = ks * 64 + (lane >> 4) * 16;
      bfrag ah[4], al[4], bh[4], bl[4];
#pragma unroll
      for (int m = 0; m < 4; ++m) {
        const int r = wr * 64 + m * 16 + (lane & 15);
        const int off = r * 128 + SWZ(r, kb);
        ah[m] = *reinterpret_cast<const bfrag*>(Ahi + off);
        al[m] = *reinterpret_cast<const bfrag*>(Alo + off);
      }
#pragma unroll
      for (int n = 0; n < 4; ++n) {
        const int r = wc * 64 + n * 16 + (lane & 15);
        const int off = r * 128 + SWZ(r, kb);
        bh[n] = *reinterpret_cast<const bfrag*>(Bhi + off);
        bl[n] = *reinterpret_cast<const bfrag*>(Blo + off);
      }
#pragma unroll
      for (int m = 0; m < 4; ++m)
#pragma unroll
        for (int n = 0; n < 4; ++n) {
          acc[m][n] = __builtin_amdgcn_mfma_f32_16x16x32_bf16(ah[m], bh[n], acc[m][n], 0, 0, 0);
          acc[m][n] = __builtin_amdgcn_mfma_f32_16x16x32_bf16(ah[m], bl[n], acc[m][n], 0, 0, 0);
          acc[m][n] = __builtin_amdgcn_mfma_f32_16x16x32_bf16(al[m], bh[n], acc[m][n], 0, 0, 0);
        }
    }
  }

  const int col = lane & 15, rq = (lane >> 4) * 4;
#pragma unroll
  for (int m = 0; m < 4; ++m)
#pragma unroll
    for (int n = 0; n < 4; ++n) {
      const int gr = Ro + wr * 64 + m * 16 + rq;
      const int gc = Co + wc * 64 + n * 16 + col;
#pragma unroll
      for (int j = 0; j < 4; ++j)
        out[(size_t)(gr + j) * N_CTX + gc] = acc[m][n][j];
      if (bx != by) {
        *reinterpret_cast<float4*>(out + (size_t)gc * N_CTX + gr) =
            make_float4(acc[m][n][0], acc[m][n][1], acc[m][n][2], acc[m][n][3]);
      }
    }
}

// ---------------------------------------------------------------------------
// Kernel 3: scan. R15: 1-barrier binary search (double-buffered reduce),
// ballot-aggregated candidate append, and global work-list append (n<<6|slot)
// for the wave-per-candidate repair. Classification semantics verbatim.
// ---------------------------------------------------------------------------
__global__ __launch_bounds__(256) void topk_scan(
    float* __restrict__ att, int* __restrict__ candM, int* __restrict__ cnt_g,
    int* __restrict__ glist, int* __restrict__ gcount) {
  __shared__ unsigned red[2][4];
  __shared__ int lcnt, lg;

  const int n = blockIdx.x;
  const int t = threadIdx.x;
  const int wid = t >> 6, lane = t & 63;
  float* row = att + (size_t)n * N_CTX;

  float ar[16], tr[16];
  unsigned ur[16];
#pragma unroll
  for (int i = 0; i < 4; ++i) {
    float4 v4 = *reinterpret_cast<const float4*>(row + (size_t)(i * 256 + t) * 4);
    float tmp[4] = {v4.x, v4.y, v4.z, v4.w};
#pragma unroll
    for (int j = 0; j < 4; ++j) {
      float a = tmp[j];
      float tt = (a > EPS_NN) ? a : 0.0f;
      ar[i * 4 + j] = a;
      tr[i * 4 + j] = tt;
      ur[i * 4 + j] = __float_as_uint(tt);
    }
  }
  if (t == 0) { lcnt = 0; lg = 0; }

  unsigned lo = 0u, hi = 0x7F800000u;
  int buf = 0;
  while (lo < hi) {
    unsigned mid = lo + ((hi - lo) >> 1);
    unsigned c = 0;
#pragma unroll
    for (int i = 0; i < 16; ++i) c += (ur[i] > mid) ? 1u : 0u;
#pragma unroll
    for (int off = 32; off; off >>= 1) c += __shfl_down(c, off, 64);
    if (lane == 0) red[buf][wid] = c;
    __syncthreads();
    unsigned tot = red[buf][0] + red[buf][1] + red[buf][2] + red[buf][3];
    if (tot < TOPK_K) hi = mid; else lo = mid + 1;
    buf ^= 1;
  }
  const float vk = __uint_as_float(lo);
  const bool nearEps = (vk <= EPS_NN + 2.0f * DELTA);
  __syncthreads();   // lcnt/lg init visible; red no longer needed

  unsigned myg = 0;
#pragma unroll
  for (int i = 0; i < 16; ++i) {
    const int blk = i >> 2, j = i & 3;
    const int m = (blk * 256 + t) * 4 + j;
    const float a = ar[i], tt = tr[i];
    const bool isEps = fabsf(a - EPS_NN) <= DELTA;
    const bool isOrd = (tt > 0.f) && (fabsf(tt - vk) <= DELTA);
    const bool cand = isOrd || (isEps && nearEps);
    const bool defIn = (tt > vk + DELTA) && !cand;
    tr[i] = defIn ? tt : 0.f;
    myg += defIn ? 1u : 0u;
    // ballot-aggregated append: one LDS atomic per wave per i
    unsigned long long mask = __ballot(cand);
    if (mask) {
      int base = 0;
      if (lane == 0) base = atomicAdd(&lcnt, (int)__popcll(mask));
      base = __shfl(base, 0, 64);
      if (cand) {
        int pos = base + (int)__popcll(mask & ((1ull << lane) - 1ull));
        if (pos < CAP) candM[n * CAP + pos] = m;
      }
    }
  }
#pragma unroll
  for (int off = 32; off; off >>= 1) myg += __shfl_down(myg, off, 64);
  if (lane == 0) atomicAdd(&lg, (int)myg);

#pragma unroll
  for (int i = 0; i < 4; ++i) {
    *reinterpret_cast<float4*>(row + (size_t)(i * 256 + t) * 4) =
        make_float4(tr[i * 4], tr[i * 4 + 1], tr[i * 4 + 2], tr[i * 4 + 3]);
  }
  __syncthreads();
  const int c = (lcnt < CAP) ? lcnt : CAP;
  if (t == 0) {
    cnt_g[2 * n] = c;
    cnt_g[2 * n + 1] = lg;
  }
  // append this row's candidate slots to the global work list
  if (t < c) {
    int gpos = atomicAdd(gcount, 1);
    glist[gpos] = (n << 6) | t;
  }
}

// ---------------------------------------------------------------------------
// Kernel 4a: exact repair, ONE WAVE PER CANDIDATE (grid-stride over glist).
// All 64 lanes redundantly run the LOCKED chain ((cn*w)*sA vs (cm*w)*sB,
// k ascending via fmaf — verbatim) with wave-uniform (broadcast) loads.
// ---------------------------------------------------------------------------
__global__ __launch_bounds__(256) void repair_compute(
    const float* __restrict__ ctx, const float* __restrict__ w,
    const float* __restrict__ invr, const int* __restrict__ candM,
    const int* __restrict__ glist, const int* __restrict__ gcount,
    float* __restrict__ teV) {
  const int wslot = blockIdx.x * 4 + (threadIdx.x >> 6);
  const int nw = gridDim.x * 4;
  int total = gcount[0];
  if (total > N_CTX * CAP) total = N_CTX * CAP;

  for (int idx = wslot; idx < total; idx += nw) {
    const int ent = glist[idx];
    const int n = ent >> 6, pos = ent & 63;
    const int m = candM[n * CAP + pos];
    const float4* cn4 = reinterpret_cast<const float4*>(ctx + (size_t)n * DIM);
    const float4* cm4 = reinterpret_cast<const float4*>(ctx + (size_t)m * DIM);
    float e = 0.f;
    for (int p = 0; p < NPERS; ++p) {
      const float sA = invr[(size_t)p * N_CTX + n];
      const float sB = invr[(size_t)p * N_CTX + m];
      const float4* w4 = reinterpret_cast<const float4*>(w + (size_t)p * DIM);
#pragma unroll 4
      for (int q = 0; q < DIM / 4; ++q) {
        const float4 a = cn4[q], b = cm4[q], ww = w4[q];
        e = fmaf((a.x * ww.x) * sA, (b.x * ww.x) * sB, e);
        e = fmaf((a.y * ww.y) * sA, (b.y * ww.y) * sB, e);
        e = fmaf((a.z * ww.z) * sA, (b.z * ww.z) * sB, e);
        e = fmaf((a.w * ww.w) * sA, (b.w * ww.w) * sB, e);
      }
    }
    if ((threadIdx.x & 63) == 0)
      teV[n * CAP + pos] = (e > EPS_NN) ? e : 0.f;
  }
}

// ---------------------------------------------------------------------------
// Kernel 4b: per-row selection (rank by value desc, index asc) + patch.
// Semantics verbatim from R14's repair_select tail.
// ---------------------------------------------------------------------------
__global__ __launch_bounds__(64) void select_kernel(
    const int* __restrict__ candM, const int* __restrict__ cnt_g,
    const float* __restrict__ teV, float* __restrict__ att) {
  const int n = blockIdx.x;
  const int c = cnt_g[2 * n];
  if (c == 0) return;
  const int slots = TOPK_K - cnt_g[2 * n + 1];

  __shared__ float te_s[CAP];
  __shared__ int m_s[CAP];

  const int j = threadIdx.x;
  if (j < c) {
    m_s[j] = candM[n * CAP + j];
    te_s[j] = teV[n * CAP + j];
  }
  __syncthreads();
  if (j < c) {
    const int m = m_s[j];
    const float te = te_s[j];
    int rank = 0;
    for (int i = 0; i < c; ++i) {
      if (i == j) continue;
      rank += ((te_s[i] > te) || (te_s[i] == te && m_s[i] < m)) ? 1 : 0;
    }
    if (rank < slots) att[(size_t)n * N_CTX + m] = te;
  }
}

// ---------------------------------------------------------------------------
extern "C" void kernel_launch(void* const* d_in, const int* in_sizes, int n_in,
                              void* d_out, int out_size, void* d_ws, size_t ws_size,
                              hipStream_t stream) {
  const float* ctx = (const float*)d_in[0];   // (4096, 512)
  const float* w   = (const float*)d_in[1];   // (16, 512)
  float* out = (float*)d_out;                 // (4096, 4096)

  // ws: invr 256K | cnt 32K | candM 1M | teV 1M | glist 1M | gcount 4K | Fhi 64M | Flo 64M
  const size_t OFF_CNT = 262144;
  const size_t OFF_CAND = OFF_CNT + 32768;
  const size_t OFF_TEV = OFF_CAND + 1048576;
  const size_t OFF_GL = OFF_TEV + 1048576;
  const size_t OFF_GC = OFF_GL + 1048576;
  const size_t OFF_FHI = OFF_GC + 4096;
  const size_t FSZ = (size_t)32 * NKSTEP * CHUNK;       // 67108864
  float* invr = (float*)d_ws;
  int* cnt_g = (int*)((char*)d_ws + OFF_CNT);
  int* candM = (int*)((char*)d_ws + OFF_CAND);
  float* teV = (float*)((char*)d_ws + OFF_TEV);
  int* glist = (int*)((char*)d_ws + OFF_GL);
  int* gcount = (int*)((char*)d_ws + OFF_GC);
  unsigned short* Fhi = (unsigned short*)((char*)d_ws + OFF_FHI);
  unsigned short* Flo = (unsigned short*)((char*)d_ws + OFF_FHI + FSZ);
  const bool haveF = ws_size >= OFF_FHI + 2 * FSZ;

  if (haveF) {
    split_norms_kernel<<<(N_CTX * 64) / 256, 256, 0, stream>>>(ctx, w, invr, Fhi, Flo, gcount);
    att_gemm_fast<<<528, 256, 0, stream>>>(Fhi, Flo, out);
  } else {
    norms_kernel<<<(NPERS * N_CTX) / 4, 256, 0, stream>>>(ctx, w, invr, gcount);
    dim3 grid(N_CTX / BM, N_CTX / BM);
    att_gemm<<<grid, 256, 0, stream>>>(ctx, w, invr, out);
  }

  topk_scan<<<N_CTX, 256, 0, stream>>>(out, candM, cnt_g, glist, gcount);
  repair_compute<<<2048, 256, 0, stream>>>(ctx, w, invr, candM, glist, gcount, teV);
  select_kernel<<<N_CTX, 64, 0, stream>>>(candM, cnt_g, teV, out);
}

// Round 16
// 667.365 us; speedup vs baseline: 2.3610x; 2.3610x over previous
//
#include <hip/hip_runtime.h>
#include <math.h>
#include <stdint.h>

#define N_CTX 4096
#define DIM 512
#define NPERS 16
#define KTOT (NPERS * DIM)   // 8192
#define EPS_NN 0.1f
#define TOPK_K 30

#define DELTA 1e-3f          // ambiguity margin; 1-product GEMM eps <= 2.44e-4
                             // (rigorous: 2^-8 * ||f|| ||g|| = 2^-8 * 0.0625),
                             // 2*eps = 4.9e-4 < DELTA  => classification exact
#define CAP 64               // max candidates per row

#define BM 128               // MFMA output tile
#define BK 64                // K-step (bf16 elems)
#define NKSTEP (KTOT / BK)   // 128
#define CHUNK 16384          // bytes per (panel, k-step) LDS image

typedef __attribute__((ext_vector_type(8))) short bfrag;   // 8 bf16 = 4 VGPR
typedef __attribute__((ext_vector_type(4))) float f32x4;

// round-to-nearest-even float -> bf16 bits
__device__ __forceinline__ unsigned short f2bf(float f) {
  unsigned u = __float_as_uint(f);
  unsigned r = u + 0x7FFFu + ((u >> 16) & 1u);
  return (unsigned short)(r >> 16);
}

#define SWZ(r, b) ((b) ^ (((r) & 7) << 4))

// stage 1 KB: 64 lanes x 16 B. ldst = wave-uniform LDS base; HW adds lane*16.
__device__ __forceinline__ void stage1k(const char* gsrc, char* ldst, int lane) {
#if __has_builtin(__builtin_amdgcn_global_load_lds)
  __builtin_amdgcn_global_load_lds(
      (const __attribute__((address_space(1))) unsigned int*)(uintptr_t)(gsrc + lane * 16),
      (__attribute__((address_space(3))) unsigned int*)(uintptr_t)ldst, 16, 0, 0);
#else
  *reinterpret_cast<uint4*>(ldst + lane * 16) =
      *reinterpret_cast<const uint4*>(gsrc + lane * 16);
#endif
}

// ---------------------------------------------------------------------------
// Kernel 1 (fallback only): invr[p][n] = 0.25 / max(||c_n * w_p||, 1e-12)
// ---------------------------------------------------------------------------
__global__ __launch_bounds__(256) void norms_kernel(
    const float* __restrict__ ctx, const float* __restrict__ w,
    float* __restrict__ invr) {
  int wid = threadIdx.x >> 6;
  int lane = threadIdx.x & 63;
  int gid = blockIdx.x * 4 + wid;          // 0 .. 65535
  int p = gid >> 12;
  int n = gid & (N_CTX - 1);
  const float4* c4 = reinterpret_cast<const float4*>(ctx + (size_t)n * DIM + lane * 8);
  const float4* w4 = reinterpret_cast<const float4*>(w + (size_t)p * DIM + lane * 8);
  float4 c0 = c4[0], c1 = c4[1];
  float4 w0 = w4[0], w1 = w4[1];
  float s = 0.f, v;
  v = c0.x * w0.x; s = fmaf(v, v, s);
  v = c0.y * w0.y; s = fmaf(v, v, s);
  v = c0.z * w0.z; s = fmaf(v, v, s);
  v = c0.w * w0.w; s = fmaf(v, v, s);
  v = c1.x * w1.x; s = fmaf(v, v, s);
  v = c1.y * w1.y; s = fmaf(v, v, s);
  v = c1.z * w1.z; s = fmaf(v, v, s);
  v = c1.w * w1.w; s = fmaf(v, v, s);
#pragma unroll
  for (int off = 32; off; off >>= 1) s += __shfl_down(s, off, 64);
  if (lane == 0) invr[(size_t)p * N_CTX + n] = 0.25f / fmaxf(sqrtf(s), 1e-12f);
}

// ---------------------------------------------------------------------------
// Kernel 1+1b FUSED: norms (bit-identical chain) + bf16-hi split into the
// panel-swizzled LDS-image layout. R16: Flo dropped entirely (1-product GEMM).
// ---------------------------------------------------------------------------
__global__ __launch_bounds__(256) void split_norms_kernel(
    const float* __restrict__ ctx, const float* __restrict__ w,
    float* __restrict__ invr, unsigned short* __restrict__ Fhi) {
  const int tid = blockIdx.x * 256 + threadIdx.x;   // 0 .. 4096*64-1
  const int n = tid >> 6;                 // wave-uniform (wave = 64 aligned)
  const int db = tid & 63;                // lane = 8-col block within 512-dim
  const int d0 = db * 8;
  const int P = n >> 7;                   // panel
  const int r = n & 127;                  // row within panel
  const int sl = db & 7;                  // 16B slot within k-step chunk
  const int swzoff = r * 128 + ((sl * 16) ^ ((r & 7) << 4));

  const float4 c0 = *reinterpret_cast<const float4*>(ctx + (size_t)n * DIM + d0);
  const float4 c1 = *reinterpret_cast<const float4*>(ctx + (size_t)n * DIM + d0 + 4);

#pragma unroll
  for (int p = 0; p < NPERS; ++p) {
    const float4 w0 = *reinterpret_cast<const float4*>(w + (size_t)p * DIM + d0);
    const float4 w1 = *reinterpret_cast<const float4*>(w + (size_t)p * DIM + d0 + 4);

    float pr[8] = {c0.x * w0.x, c0.y * w0.y, c0.z * w0.z, c0.w * w0.w,
                   c1.x * w1.x, c1.y * w1.y, c1.z * w1.z, c1.w * w1.w};

    // norm: identical fmaf order + identical reduce tree as norms_kernel
    float s = 0.f;
#pragma unroll
    for (int j = 0; j < 8; ++j) s = fmaf(pr[j], pr[j], s);
#pragma unroll
    for (int off = 32; off; off >>= 1) s += __shfl_down(s, off, 64);
    const float stot = __shfl(s, 0, 64);
    const float sc = 0.25f / fmaxf(sqrtf(stot), 1e-12f);
    if (db == 0) invr[(size_t)p * N_CTX + n] = sc;

    unsigned hb[8];
#pragma unroll
    for (int j = 0; j < 8; ++j) hb[j] = f2bf(pr[j] * sc);   // == (c*w)*sc
    uint4 hv = make_uint4(hb[0] | (hb[1] << 16), hb[2] | (hb[3] << 16),
                          hb[4] | (hb[5] << 16), hb[6] | (hb[7] << 16));
    const int kstep = p * 8 + (db >> 3);           // k-step index
    const size_t base = (size_t)(P * 128 + kstep) * CHUNK + swzoff;
    *reinterpret_cast<uint4*>((char*)Fhi + base) = hv;
  }
}

// ---------------------------------------------------------------------------
// Kernel 2 (fast): att ~= Fhi Fhi^T via bf16 MFMA, SINGLE product.
// m97 2-barrier structure, XCD-swizzled triangular grid (validated R14).
// LDS down to 32 KB -> 3 blocks/CU for cross-block barrier overlap.
// Worst-case |approx - exact| <= 2^-8 * 0.0625 = 2.44e-4 < DELTA/2.
// ---------------------------------------------------------------------------
__global__ __launch_bounds__(256, 3) void att_gemm_fast(
    const unsigned short* __restrict__ Fhi, float* __restrict__ out) {
  const int bid0 = blockIdx.x;
  int bid = (bid0 & 7) * 66 + (bid0 >> 3);   // XCD-contiguous tile runs
  int by = 0;
  while (bid >= (by + 1) * 32 - ((by + 1) * by) / 2) ++by;
  const int bx = by + (bid - (by * 32 - (by * (by - 1)) / 2));

  __shared__ __align__(16) char Ahi[CHUNK];
  __shared__ __align__(16) char Bhi[CHUNK];

  const int t = threadIdx.x;
  const int lane = t & 63, wid = t >> 6;
  const int wr = wid >> 1, wc = wid & 1;
  const int woff = __builtin_amdgcn_readfirstlane(wid * 4096);

  const char* gAh = (const char*)Fhi + (size_t)by * NKSTEP * CHUNK + woff;
  const char* gBh = (const char*)Fhi + (size_t)bx * NKSTEP * CHUNK + woff;

  f32x4 acc[4][4] = {};

  for (int s = 0; s < NKSTEP; ++s) {
    const size_t so = (size_t)s * CHUNK;
#pragma unroll
    for (int i = 0; i < 4; ++i) {
      stage1k(gAh + so + i * 1024, Ahi + woff + i * 1024, lane);
      stage1k(gBh + so + i * 1024, Bhi + woff + i * 1024, lane);
    }
    __syncthreads();   // vmcnt drained before barrier: staged data visible

#pragma unroll
    for (int ks = 0; ks < 2; ++ks) {
      const int kb = ks * 64 + (lane >> 4) * 16;
      bfrag ah[4], bh[4];
#pragma unroll
      for (int m = 0; m < 4; ++m) {
        const int r = wr * 64 + m * 16 + (lane & 15);
        ah[m] = *reinterpret_cast<const bfrag*>(Ahi + r * 128 + SWZ(r, kb));
      }
#pragma unroll
      for (int n2 = 0; n2 < 4; ++n2) {
        const int r = wc * 64 + n2 * 16 + (lane & 15);
        bh[n2] = *reinterpret_cast<const bfrag*>(Bhi + r * 128 + SWZ(r, kb));
      }
#pragma unroll
      for (int m = 0; m < 4; ++m)
#pragma unroll
        for (int n2 = 0; n2 < 4; ++n2)
          acc[m][n2] = __builtin_amdgcn_mfma_f32_16x16x32_bf16(ah[m], bh[n2], acc[m][n2], 0, 0, 0);
    }
    __syncthreads();   // all waves done reading before next overwrite
  }

  const int Ro = by * BM, Co = bx * BM;
  const int col = lane & 15, rq = (lane >> 4) * 4;
#pragma unroll
  for (int m = 0; m < 4; ++m)
#pragma unroll
    for (int n2 = 0; n2 < 4; ++n2) {
      const int gr = Ro + wr * 64 + m * 16 + rq;
      const int gc = Co + wc * 64 + n2 * 16 + col;
#pragma unroll
      for (int j = 0; j < 4; ++j)
        out[(size_t)(gr + j) * N_CTX + gc] = acc[m][n2][j];
      if (bx != by) {
        *reinterpret_cast<float4*>(out + (size_t)gc * N_CTX + gr) =
            make_float4(acc[m][n2][0], acc[m][n2][1], acc[m][n2][2], acc[m][n2][3]);
      }
    }
}

// ---------------------------------------------------------------------------
// Kernel 2 (fallback): on-the-fly split + 3-product MFMA (ws too small path).
// ---------------------------------------------------------------------------
__device__ __forceinline__ void stage_half(char* __restrict__ hi_base,
                                           char* __restrict__ lo_base,
                                           const float4* cv, const float4* wv,
                                           float s, int r, int h) {
  unsigned hu[16], lu[16];
#pragma unroll
  for (int i = 0; i < 8; ++i) {
    float f[4] = {cv[i].x * wv[i].x * s, cv[i].y * wv[i].y * s,
                  cv[i].z * wv[i].z * s, cv[i].w * wv[i].w * s};
    unsigned hb[4], lb[4];
#pragma unroll
    for (int j = 0; j < 4; ++j) {
      hb[j] = f2bf(f[j]);
      float hf = __uint_as_float(hb[j] << 16);
      lb[j] = f2bf(f[j] - hf);
    }
    hu[2 * i] = hb[0] | (hb[1] << 16);
    hu[2 * i + 1] = hb[2] | (hb[3] << 16);
    lu[2 * i] = lb[0] | (lb[1] << 16);
    lu[2 * i + 1] = lb[2] | (lb[3] << 16);
  }
#pragma unroll
  for (int c = 0; c < 4; ++c) {
    int boff = r * 128 + SWZ(r, h * 64 + c * 16);
    *reinterpret_cast<uint4*>(hi_base + boff) =
        make_uint4(hu[4 * c], hu[4 * c + 1], hu[4 * c + 2], hu[4 * c + 3]);
    *reinterpret_cast<uint4*>(lo_base + boff) =
        make_uint4(lu[4 * c], lu[4 * c + 1], lu[4 * c + 2], lu[4 * c + 3]);
  }
}

__global__ __launch_bounds__(256, 2) void att_gemm(
    const float* __restrict__ ctx, const float* __restrict__ w,
    const float* __restrict__ invr, float* __restrict__ out) {
  const int bx = blockIdx.x, by = blockIdx.y;
  if (by > bx) return;

  __shared__ __align__(16) char Ahi[BM * 128];
  __shared__ __align__(16) char Alo[BM * 128];
  __shared__ __align__(16) char Bhi[BM * 128];
  __shared__ __align__(16) char Blo[BM * 128];

  const int t = threadIdx.x;
  const int lane = t & 63, wid = t >> 6;
  const int wr = wid >> 1, wc = wid & 1;
  const int Ro = by * BM, Co = bx * BM;
  const int srow = t >> 1;
  const int sh = t & 1;

  f32x4 acc[4][4] = {};

  for (int k0 = 0; k0 < KTOT; k0 += BK) {
    const int p = k0 >> 9;
    const int d0 = (k0 & (DIM - 1)) + sh * 32;

    float4 cva[8], cvb[8], wv[8];
    const float* wrow = w + (size_t)p * DIM + d0;
    const float* arow = ctx + (size_t)(Ro + srow) * DIM + d0;
    const float* brow = ctx + (size_t)(Co + srow) * DIM + d0;
#pragma unroll
    for (int i = 0; i < 8; ++i) {
      wv[i] = *reinterpret_cast<const float4*>(wrow + 4 * i);
      cva[i] = *reinterpret_cast<const float4*>(arow + 4 * i);
      cvb[i] = *reinterpret_cast<const float4*>(brow + 4 * i);
    }
    const float sA = invr[(size_t)p * N_CTX + Ro + srow];
    const float sB = invr[(size_t)p * N_CTX + Co + srow];

    __syncthreads();
    stage_half(Ahi, Alo, cva, wv, sA, srow, sh);
    stage_half(Bhi, Blo, cvb, wv, sB, srow, sh);
    __syncthreads();

#pragma unroll
    for (int ks = 0; ks < 2; ++ks) {
      const int kb = ks * 64 + (lane >> 4) * 16;
      bfrag ah[4], al[4], bh[4], bl[4];
#pragma unroll
      for (int m = 0; m < 4; ++m) {
        const int r = wr * 64 + m * 16 + (lane & 15);
        const int off = r * 128 + SWZ(r, kb);
        ah[m] = *reinterpret_cast<const bfrag*>(Ahi + off);
        al[m] = *reinterpret_cast<const bfrag*>(Alo + off);
      }
#pragma unroll
      for (int n = 0; n < 4; ++n) {
        const int r = wc * 64 + n * 16 + (lane & 15);
        const int off = r * 128 + SWZ(r, kb);
        bh[n] = *reinterpret_cast<const bfrag*>(Bhi + off);
        bl[n] = *reinterpret_cast<const bfrag*>(Blo + off);
      }
#pragma unroll
      for (int m = 0; m < 4; ++m)
#pragma unroll
        for (int n = 0; n < 4; ++n) {
          acc[m][n] = __builtin_amdgcn_mfma_f32_16x16x32_bf16(ah[m], bh[n], acc[m][n], 0, 0, 0);
          acc[m][n] = __builtin_amdgcn_mfma_f32_16x16x32_bf16(ah[m], bl[n], acc[m][n], 0, 0, 0);
          acc[m][n] = __builtin_amdgcn_mfma_f32_16x16x32_bf16(al[m], bh[n], acc[m][n], 0, 0, 0);
        }
    }
  }

  const int col = lane & 15, rq = (lane >> 4) * 4;
#pragma unroll
  for (int m = 0; m < 4; ++m)
#pragma unroll
    for (int n = 0; n < 4; ++n) {
      const int gr = Ro + wr * 64 + m * 16 + rq;
      const int gc = Co + wc * 64 + n * 16 + col;
#pragma unroll
      for (int j = 0; j < 4; ++j)
        out[(size_t)(gr + j) * N_CTX + gc] = acc[m][n][j];
      if (bx != by) {
        *reinterpret_cast<float4*>(out + (size_t)gc * N_CTX + gr) =
            make_float4(acc[m][n][0], acc[m][n][1], acc[m][n][2], acc[m][n][3]);
      }
    }
}

// ---------------------------------------------------------------------------
// Kernel 3: scan — R15's fast version (coalesced, 1-barrier search, ballot
// append) minus the global work list. Classification semantics verbatim.
// ---------------------------------------------------------------------------
__global__ __launch_bounds__(256) void topk_scan(
    float* __restrict__ att, int* __restrict__ candM,
    int* __restrict__ cnt_g) {
  __shared__ unsigned red[2][4];
  __shared__ int lcnt, lg;

  const int n = blockIdx.x;
  const int t = threadIdx.x;
  const int wid = t >> 6, lane = t & 63;
  float* row = att + (size_t)n * N_CTX;

  float ar[16], tr[16];
  unsigned ur[16];
#pragma unroll
  for (int i = 0; i < 4; ++i) {
    float4 v4 = *reinterpret_cast<const float4*>(row + (size_t)(i * 256 + t) * 4);
    float tmp[4] = {v4.x, v4.y, v4.z, v4.w};
#pragma unroll
    for (int j = 0; j < 4; ++j) {
      float a = tmp[j];
      float tt = (a > EPS_NN) ? a : 0.0f;
      ar[i * 4 + j] = a;
      tr[i * 4 + j] = tt;
      ur[i * 4 + j] = __float_as_uint(tt);
    }
  }
  if (t == 0) { lcnt = 0; lg = 0; }

  unsigned lo = 0u, hi = 0x7F800000u;
  int buf = 0;
  while (lo < hi) {
    unsigned mid = lo + ((hi - lo) >> 1);
    unsigned c = 0;
#pragma unroll
    for (int i = 0; i < 16; ++i) c += (ur[i] > mid) ? 1u : 0u;
#pragma unroll
    for (int off = 32; off; off >>= 1) c += __shfl_down(c, off, 64);
    if (lane == 0) red[buf][wid] = c;
    __syncthreads();
    unsigned tot = red[buf][0] + red[buf][1] + red[buf][2] + red[buf][3];
    if (tot < TOPK_K) hi = mid; else lo = mid + 1;
    buf ^= 1;
  }
  const float vk = __uint_as_float(lo);
  const bool nearEps = (vk <= EPS_NN + 2.0f * DELTA);
  __syncthreads();   // lcnt/lg init visible

  unsigned myg = 0;
#pragma unroll
  for (int i = 0; i < 16; ++i) {
    const int blk = i >> 2, j = i & 3;
    const int m = (blk * 256 + t) * 4 + j;
    const float a = ar[i], tt = tr[i];
    const bool isEps = fabsf(a - EPS_NN) <= DELTA;
    const bool isOrd = (tt > 0.f) && (fabsf(tt - vk) <= DELTA);
    const bool cand = isOrd || (isEps && nearEps);
    const bool defIn = (tt > vk + DELTA) && !cand;
    tr[i] = defIn ? tt : 0.f;
    myg += defIn ? 1u : 0u;
    unsigned long long mask = __ballot(cand);
    if (mask) {
      int base = 0;
      if (lane == 0) base = atomicAdd(&lcnt, (int)__popcll(mask));
      base = __shfl(base, 0, 64);
      if (cand) {
        int pos = base + (int)__popcll(mask & ((1ull << lane) - 1ull));
        if (pos < CAP) candM[n * CAP + pos] = m;
      }
    }
  }
#pragma unroll
  for (int off = 32; off; off >>= 1) myg += __shfl_down(myg, off, 64);
  if (lane == 0) atomicAdd(&lg, (int)myg);

#pragma unroll
  for (int i = 0; i < 4; ++i) {
    *reinterpret_cast<float4*>(row + (size_t)(i * 256 + t) * 4) =
        make_float4(tr[i * 4], tr[i * 4 + 1], tr[i * 4 + 2], tr[i * 4 + 3]);
  }
  __syncthreads();
  if (t == 0) {
    cnt_g[2 * n] = (lcnt < CAP) ? lcnt : CAP;
    cnt_g[2 * n + 1] = lg;
  }
}

// ---------------------------------------------------------------------------
// Kernel 4: exact repair + select — R14's lane-per-candidate version verbatim
// (locked chain: (cn*w)*sA vs (cm*w)*sB, k ascending via fmaf).
// ---------------------------------------------------------------------------
__global__ __launch_bounds__(64) void repair_select(
    const float* __restrict__ ctx, const float* __restrict__ w,
    const float* __restrict__ invr, const int* __restrict__ candM,
    const int* __restrict__ cnt_g, float* __restrict__ att) {
  const int n = blockIdx.x;
  const int c = cnt_g[2 * n];
  if (c == 0) return;
  const int slots = TOPK_K - cnt_g[2 * n + 1];

  __shared__ float te_s[CAP];
  __shared__ int m_s[CAP];

  const int j = threadIdx.x;
  float te = -1.f;
  int m = -1;
  if (j < c) {
    m = candM[n * CAP + j];
    const float4* cn4 = reinterpret_cast<const float4*>(ctx + (size_t)n * DIM);
    const float4* cm4 = reinterpret_cast<const float4*>(ctx + (size_t)m * DIM);
    float e = 0.f;
    for (int p = 0; p < NPERS; ++p) {
      const float sA = invr[(size_t)p * N_CTX + n];
      const float sB = invr[(size_t)p * N_CTX + m];
      const float4* w4 = reinterpret_cast<const float4*>(w + (size_t)p * DIM);
#pragma unroll 4
      for (int q = 0; q < DIM / 4; ++q) {
        const float4 a = cn4[q], b = cm4[q], ww = w4[q];
        e = fmaf((a.x * ww.x) * sA, (b.x * ww.x) * sB, e);
        e = fmaf((a.y * ww.y) * sA, (b.y * ww.y) * sB, e);
        e = fmaf((a.z * ww.z) * sA, (b.z * ww.z) * sB, e);
        e = fmaf((a.w * ww.w) * sA, (b.w * ww.w) * sB, e);
      }
    }
    te = (e > EPS_NN) ? e : 0.f;
  }
  m_s[j] = m;
  te_s[j] = te;
  __syncthreads();
  if (j < c) {
    int rank = 0;
    for (int i = 0; i < c; ++i) {
      if (i == j) continue;
      rank += ((te_s[i] > te) || (te_s[i] == te && m_s[i] < m)) ? 1 : 0;
    }
    if (rank < slots) att[(size_t)n * N_CTX + m] = te;
  }
}

// ---------------------------------------------------------------------------
extern "C" void kernel_launch(void* const* d_in, const int* in_sizes, int n_in,
                              void* d_out, int out_size, void* d_ws, size_t ws_size,
                              hipStream_t stream) {
  const float* ctx = (const float*)d_in[0];   // (4096, 512)
  const float* w   = (const float*)d_in[1];   // (16, 512)
  float* out = (float*)d_out;                 // (4096, 4096)

  // ws: invr 256KB | cnt_g 32KB | candM 1MB | Fhi 64MB
  const size_t OFF_CNT = 262144;
  const size_t OFF_CAND = OFF_CNT + 32768;
  const size_t OFF_FHI = OFF_CAND + 1048576;
  const size_t FSZ = (size_t)32 * NKSTEP * CHUNK;       // 67108864
  float* invr = (float*)d_ws;
  int* cnt_g = (int*)((char*)d_ws + OFF_CNT);
  int* candM = (int*)((char*)d_ws + OFF_CAND);
  unsigned short* Fhi = (unsigned short*)((char*)d_ws + OFF_FHI);
  const bool haveF = ws_size >= OFF_FHI + FSZ;

  if (haveF) {
    split_norms_kernel<<<(N_CTX * 64) / 256, 256, 0, stream>>>(ctx, w, invr, Fhi);
    att_gemm_fast<<<528, 256, 0, stream>>>(Fhi, out);
  } else {
    norms_kernel<<<(NPERS * N_CTX) / 4, 256, 0, stream>>>(ctx, w, invr);
    dim3 grid(N_CTX / BM, N_CTX / BM);
    att_gemm<<<grid, 256, 0, stream>>>(ctx, w, invr, out);
  }

  topk_scan<<<N_CTX, 256, 0, stream>>>(out, candM, cnt_g);
  repair_select<<<N_CTX, 64, 0, stream>>>(ctx, w, invr, candM, cnt_g, out);
}